// Round 1
// baseline (541.640 us; speedup 1.0000x reference)
//
#include <hip/hip_runtime.h>
#include <math.h>

#define BB 8
#define NN 2000
#define CC 81
#define MAXI 100
#define WPB 32              // 64-bit words per bitmask row (2048 bits >= 2000)

static constexpr float kMinConf = 0.7f;
static constexpr float kNmsThr  = 0.3f;

// ---------------- workspace layout (bytes) ----------------
// BN = 16000
// boxes  : [0,       256000)   BN*4 f32
// key    : [256000,  320000)   BN f32  (score if valid else -inf)
// cls    : [320000,  384000)   BN i32
// sboxes : [384000,  640000)   BN*4 f32 (sorted)
// sscore : [640000,  704000)   BN f32   (sorted key)
// scls   : [704000,  768000)   BN i32   (sorted)
// vbits  : [768000,  770048)   B*32 u64 (valid bitmask in sorted order)
// sup    : [770048,  4866048)  B*N*32 u64 suppression rows

__global__ void k1_refine(const float* __restrict__ rois,
                          const float* __restrict__ probs,
                          const float* __restrict__ deltas,
                          float* __restrict__ boxes,
                          float* __restrict__ key,
                          int* __restrict__ cls,
                          unsigned long long* __restrict__ vbits) {
    int idx = blockIdx.x * blockDim.x + threadIdx.x;
    if (idx < BB * WPB) vbits[idx] = 0ull;          // zero valid bitmask each call
    if (idx >= BB * NN) return;

    const float* p = probs + (size_t)idx * CC;
    int cid = 0; float sc = p[0];
    #pragma unroll 9
    for (int c = 1; c < CC; ++c) { float v = p[c]; if (v > sc) { sc = v; cid = c; } }

    const float* d = deltas + ((size_t)idx * CC + cid) * 4;
    float dy = d[0] * 0.1f, dx = d[1] * 0.1f, dh = d[2] * 0.2f, dw = d[3] * 0.2f;

    const float* r = rois + (size_t)idx * 4;
    float y1 = r[0], x1 = r[1], y2 = r[2], x2 = r[3];
    float h = y2 - y1, w = x2 - x1;
    float cy = y1 + 0.5f * h + dy * h;
    float cx = x1 + 0.5f * w + dx * w;
    float h2 = h * expf(dh);
    float w2 = w * expf(dw);
    float oy1 = cy - 0.5f * h2, ox1 = cx - 0.5f * w2;
    float oy2 = cy + 0.5f * h2, ox2 = cx + 0.5f * w2;
    // clip to [0,1]
    oy1 = fminf(fmaxf(oy1, 0.f), 1.f);
    ox1 = fminf(fmaxf(ox1, 0.f), 1.f);
    oy2 = fminf(fmaxf(oy2, 0.f), 1.f);
    ox2 = fminf(fmaxf(ox2, 0.f), 1.f);

    bool valid = (cid > 0) && (sc >= kMinConf);
    float4 bx; bx.x = oy1; bx.y = ox1; bx.z = oy2; bx.w = ox2;
    ((float4*)boxes)[idx] = bx;
    key[idx] = valid ? sc : -INFINITY;
    cls[idx] = cid;
}

__global__ void k2_rank(const float* __restrict__ boxes,
                        const float* __restrict__ key,
                        const int* __restrict__ cls,
                        float* __restrict__ sboxes,
                        float* __restrict__ sscore,
                        int* __restrict__ scls,
                        unsigned long long* __restrict__ vbits) {
    int idx = blockIdx.x * blockDim.x + threadIdx.x;
    if (idx >= BB * NN) return;
    int b = idx / NN, i = idx - b * NN;
    const float* kb = key + (size_t)b * NN;
    float ki = kb[i];
    int rank = 0;
    const float4* k4 = (const float4*)kb;
    for (int j4 = 0; j4 < NN / 4; ++j4) {
        float4 kv = k4[j4];
        int j = j4 * 4;
        rank += (kv.x > ki) || (kv.x == ki && (j + 0) < i);
        rank += (kv.y > ki) || (kv.y == ki && (j + 1) < i);
        rank += (kv.z > ki) || (kv.z == ki && (j + 2) < i);
        rank += (kv.w > ki) || (kv.w == ki && (j + 3) < i);
    }
    int dst = b * NN + rank;
    ((float4*)sboxes)[dst] = ((const float4*)boxes)[idx];
    sscore[dst] = ki;
    scls[dst] = cls[idx];
    if (ki != -INFINITY) {
        atomicOr(&vbits[b * WPB + (rank >> 6)], 1ull << (rank & 63));
    }
}

__global__ void k3_sup(const float* __restrict__ sboxes,
                       const int* __restrict__ scls,
                       unsigned long long* __restrict__ sup) {
    int idx = blockIdx.x * blockDim.x + threadIdx.x;
    if (idx >= BB * NN * WPB) return;
    int w = idx & (WPB - 1);
    int bi = idx >> 5;
    int i = bi % NN, b = bi / NN;
    int j0 = w * 64;
    if (j0 + 63 <= i) { sup[idx] = 0ull; return; }   // only j>i bits can be set

    const float4* bxs = (const float4*)sboxes + (size_t)b * NN;
    const int* cl = scls + (size_t)b * NN;
    float4 a = bxs[i];
    int ci = cl[i];
    float aarea = (a.z - a.x) * (a.w - a.y);

    unsigned long long m = 0ull;
    int jend = min(j0 + 64, NN);
    for (int j = max(j0, i + 1); j < jend; ++j) {
        if (cl[j] != ci) continue;
        float4 bj = bxs[j];
        float iy1 = fmaxf(a.x, bj.x), ix1 = fmaxf(a.y, bj.y);
        float iy2 = fminf(a.z, bj.z), ix2 = fminf(a.w, bj.w);
        float inter = fmaxf(iy2 - iy1, 0.f) * fmaxf(ix2 - ix1, 0.f);
        float barea = (bj.z - bj.x) * (bj.w - bj.y);
        float uni = fmaxf(aarea + barea - inter, 1e-12f);
        float iou = inter / uni;
        if (iou > kNmsThr) m |= (1ull << (j - j0));
    }
    sup[idx] = m;
}

__global__ void __launch_bounds__(64) k4_scan(const unsigned long long* __restrict__ sup,
                        const unsigned long long* __restrict__ vbits,
                        const float* __restrict__ sboxes,
                        const float* __restrict__ sscore,
                        const int* __restrict__ scls,
                        float* __restrict__ out) {
    const int b = blockIdx.x;
    const int lane = threadIdx.x;
    const int wl = lane & 31;

    unsigned long long keep = vbits[b * WPB + wl];
    const unsigned long long* srow = sup + (size_t)b * NN * WPB;

    constexpr int CH = 16;
    unsigned long long bufA[CH], bufB[CH];

    #pragma unroll
    for (int t = 0; t < CH; ++t) {
        int i = t;
        bufA[t] = (i < NN) ? srow[(size_t)i * WPB + wl] : 0ull;
    }

    for (int c0 = 0; c0 < NN; c0 += 2 * CH) {
        // prefetch chunk B (rows c0+CH .. c0+2CH-1)
        #pragma unroll
        for (int t = 0; t < CH; ++t) {
            int i = c0 + CH + t;
            bufB[t] = (i < NN) ? srow[(size_t)i * WPB + wl] : 0ull;
        }
        // process chunk A
        #pragma unroll
        for (int t = 0; t < CH; ++t) {
            int i = c0 + t;
            if (i >= NN) break;
            unsigned long long kw = __shfl(keep, i >> 6);
            if ((kw >> (i & 63)) & 1ull) keep &= ~bufA[t];
        }
        // prefetch chunk A for next iter (rows c0+2CH .. c0+3CH-1)
        #pragma unroll
        for (int t = 0; t < CH; ++t) {
            int i = c0 + 2 * CH + t;
            bufA[t] = (i < NN) ? srow[(size_t)i * WPB + wl] : 0ull;
        }
        // process chunk B
        #pragma unroll
        for (int t = 0; t < CH; ++t) {
            int i = c0 + CH + t;
            if (i >= NN) break;
            unsigned long long kw = __shfl(keep, i >> 6);
            if ((kw >> (i & 63)) & 1ull) keep &= ~bufB[t];
        }
    }

    // ---- emit first 100 kept in order ----
    int cnt = __popcll(keep);
    int base = 0, total = 0;
    for (int w2 = 0; w2 < 32; ++w2) {
        int c2 = __shfl(cnt, w2);
        if (w2 < wl) base += c2;
        total += c2;
    }

    if (lane < 32) {
        unsigned long long kk = keep;
        int r = base;
        while (kk) {
            int k = __builtin_ctzll(kk);
            kk &= kk - 1;
            if (r < MAXI) {
                int j = wl * 64 + k;
                float4 bx = ((const float4*)sboxes)[b * NN + j];
                float* o = out + ((size_t)b * MAXI + r) * 6;
                o[0] = bx.x; o[1] = bx.y; o[2] = bx.z; o[3] = bx.w;
                o[4] = (float)scls[b * NN + j];
                o[5] = sscore[b * NN + j];
            }
            ++r;
        }
    }
    for (int r = total + lane; r < MAXI; r += 64) {
        float* o = out + ((size_t)b * MAXI + r) * 6;
        #pragma unroll
        for (int q = 0; q < 6; ++q) o[q] = 0.f;
    }
}

extern "C" void kernel_launch(void* const* d_in, const int* in_sizes, int n_in,
                              void* d_out, int out_size, void* d_ws, size_t ws_size,
                              hipStream_t stream) {
    const float* rois   = (const float*)d_in[0];
    const float* probs  = (const float*)d_in[1];
    const float* deltas = (const float*)d_in[2];
    float* out = (float*)d_out;

    char* ws = (char*)d_ws;
    float* boxes  = (float*)(ws + 0);
    float* key    = (float*)(ws + 256000);
    int*   cls    = (int*)  (ws + 320000);
    float* sboxes = (float*)(ws + 384000);
    float* sscore = (float*)(ws + 640000);
    int*   scls   = (int*)  (ws + 704000);
    unsigned long long* vbits = (unsigned long long*)(ws + 768000);
    unsigned long long* sup   = (unsigned long long*)(ws + 770048);

    {
        int threads = BB * NN;
        int blocks = (threads + 255) / 256;
        k1_refine<<<blocks, 256, 0, stream>>>(rois, probs, deltas, boxes, key, cls, vbits);
    }
    {
        int threads = BB * NN;
        int blocks = (threads + 255) / 256;
        k2_rank<<<blocks, 256, 0, stream>>>(boxes, key, cls, sboxes, sscore, scls, vbits);
    }
    {
        int threads = BB * NN * WPB;
        int blocks = (threads + 255) / 256;
        k3_sup<<<blocks, 256, 0, stream>>>(sboxes, scls, sup);
    }
    {
        k4_scan<<<BB, 64, 0, stream>>>(sup, vbits, sboxes, sscore, scls, out);
    }
}

// Round 2
// 221.520 us; speedup vs baseline: 2.4451x; 2.4451x over previous
//
#include <hip/hip_runtime.h>
#include <math.h>

#define BB 8
#define NN 2000
#define CC 81
#define MAXI 100
#define WPB 32              // 64-bit words per bitmask row (2048 bits >= 2000)

static constexpr float kMinConf = 0.7f;
static constexpr float kNmsThr  = 0.3f;

// ---------------- workspace layout (bytes) ----------------
// BN = 16000
// boxes  : [0,       256000)   BN*4 f32
// key    : [256000,  320000)   BN f32  (score if valid else -inf)
// cls    : [320000,  384000)   BN i32
// sboxes : [384000,  640000)   BN*4 f32 (sorted)
// sscore : [640000,  704000)   BN f32   (sorted key)
// scls   : [704000,  768000)   BN i32   (sorted)
// vbits  : [768000,  770048)   B*32 u64 (valid bitmask in sorted order)
// sup    : [770048,  4866048)  B*N*32 u64 suppression rows

__global__ void k1_refine(const float* __restrict__ rois,
                          const float* __restrict__ probs,
                          const float* __restrict__ deltas,
                          float* __restrict__ boxes,
                          float* __restrict__ key,
                          int* __restrict__ cls,
                          unsigned long long* __restrict__ vbits) {
    int idx = blockIdx.x * blockDim.x + threadIdx.x;
    if (idx < BB * WPB) vbits[idx] = 0ull;          // zero valid bitmask each call
    if (idx >= BB * NN) return;

    const float* p = probs + (size_t)idx * CC;
    int cid = 0; float sc = p[0];
    #pragma unroll 9
    for (int c = 1; c < CC; ++c) { float v = p[c]; if (v > sc) { sc = v; cid = c; } }

    const float* d = deltas + ((size_t)idx * CC + cid) * 4;
    float dy = d[0] * 0.1f, dx = d[1] * 0.1f, dh = d[2] * 0.2f, dw = d[3] * 0.2f;

    const float* r = rois + (size_t)idx * 4;
    float y1 = r[0], x1 = r[1], y2 = r[2], x2 = r[3];
    float h = y2 - y1, w = x2 - x1;
    float cy = y1 + 0.5f * h + dy * h;
    float cx = x1 + 0.5f * w + dx * w;
    float h2 = h * expf(dh);
    float w2 = w * expf(dw);
    float oy1 = cy - 0.5f * h2, ox1 = cx - 0.5f * w2;
    float oy2 = cy + 0.5f * h2, ox2 = cx + 0.5f * w2;
    // clip to [0,1]
    oy1 = fminf(fmaxf(oy1, 0.f), 1.f);
    ox1 = fminf(fmaxf(ox1, 0.f), 1.f);
    oy2 = fminf(fmaxf(oy2, 0.f), 1.f);
    ox2 = fminf(fmaxf(ox2, 0.f), 1.f);

    bool valid = (cid > 0) && (sc >= kMinConf);
    float4 bx; bx.x = oy1; bx.y = ox1; bx.z = oy2; bx.w = ox2;
    ((float4*)boxes)[idx] = bx;
    key[idx] = valid ? sc : -INFINITY;
    cls[idx] = cid;
}

__global__ void k2_rank(const float* __restrict__ boxes,
                        const float* __restrict__ key,
                        const int* __restrict__ cls,
                        float* __restrict__ sboxes,
                        float* __restrict__ sscore,
                        int* __restrict__ scls,
                        unsigned long long* __restrict__ vbits) {
    int idx = blockIdx.x * blockDim.x + threadIdx.x;
    if (idx >= BB * NN) return;
    int b = idx / NN, i = idx - b * NN;
    const float* kb = key + (size_t)b * NN;
    float ki = kb[i];
    int rank = 0;
    const float4* k4 = (const float4*)kb;
    for (int j4 = 0; j4 < NN / 4; ++j4) {
        float4 kv = k4[j4];
        int j = j4 * 4;
        rank += (kv.x > ki) || (kv.x == ki && (j + 0) < i);
        rank += (kv.y > ki) || (kv.y == ki && (j + 1) < i);
        rank += (kv.z > ki) || (kv.z == ki && (j + 2) < i);
        rank += (kv.w > ki) || (kv.w == ki && (j + 3) < i);
    }
    int dst = b * NN + rank;
    ((float4*)sboxes)[dst] = ((const float4*)boxes)[idx];
    sscore[dst] = ki;
    scls[dst] = cls[idx];
    if (ki != -INFINITY) {
        atomicOr(&vbits[b * WPB + (rank >> 6)], 1ull << (rank & 63));
    }
}

__global__ void k3_sup(const float* __restrict__ sboxes,
                       const int* __restrict__ scls,
                       unsigned long long* __restrict__ sup) {
    int idx = blockIdx.x * blockDim.x + threadIdx.x;
    if (idx >= BB * NN * WPB) return;
    int w = idx & (WPB - 1);
    int bi = idx >> 5;
    int i = bi % NN, b = bi / NN;
    int j0 = w * 64;
    if (j0 + 63 <= i) { sup[idx] = 0ull; return; }   // only j>i bits can be set

    const float4* bxs = (const float4*)sboxes + (size_t)b * NN;
    const int* cl = scls + (size_t)b * NN;
    float4 a = bxs[i];
    int ci = cl[i];
    float aarea = (a.z - a.x) * (a.w - a.y);

    unsigned long long m = 0ull;
    int jend = min(j0 + 64, NN);
    for (int j = max(j0, i + 1); j < jend; ++j) {
        if (cl[j] != ci) continue;
        float4 bj = bxs[j];
        float iy1 = fmaxf(a.x, bj.x), ix1 = fmaxf(a.y, bj.y);
        float iy2 = fminf(a.z, bj.z), ix2 = fminf(a.w, bj.w);
        float inter = fmaxf(iy2 - iy1, 0.f) * fmaxf(ix2 - ix1, 0.f);
        float barea = (bj.z - bj.x) * (bj.w - bj.y);
        float uni = fmaxf(aarea + barea - inter, 1e-12f);
        float iou = inter / uni;
        if (iou > kNmsThr) m |= (1ull << (j - j0));
    }
    sup[idx] = m;
}

__device__ __forceinline__ unsigned long long readlane_u64(unsigned long long v, int lane) {
    unsigned int lo = (unsigned int)(v & 0xffffffffull);
    unsigned int hi = (unsigned int)(v >> 32);
    lo = (unsigned int)__builtin_amdgcn_readlane((int)lo, lane);
    hi = (unsigned int)__builtin_amdgcn_readlane((int)hi, lane);
    return ((unsigned long long)hi << 32) | (unsigned long long)lo;
}

// Serial greedy scan. 2000 = 25*80: CH=25-row chunks, 80 chunks, processed as
// 40 double-buffered pairs -> no tail, no in-loop bounds checks, full unroll,
// buffers guaranteed in VGPRs (rule #20: any runtime index -> scratch -> 10x).
__global__ void __launch_bounds__(64) k4_scan(const unsigned long long* __restrict__ sup,
                        const unsigned long long* __restrict__ vbits,
                        const float* __restrict__ sboxes,
                        const float* __restrict__ sscore,
                        const int* __restrict__ scls,
                        float* __restrict__ out) {
    const int b = blockIdx.x;
    const int lane = threadIdx.x;
    const int wl = lane & 31;

    unsigned long long keep = vbits[b * WPB + wl];
    const unsigned long long* srow = sup + (size_t)b * NN * WPB;

    constexpr int CH = 25;            // 2000 / 25 = 80 chunks, even count
    unsigned long long bufA[CH], bufB[CH];

    #pragma unroll
    for (int t = 0; t < CH; ++t) bufA[t] = srow[(size_t)t * WPB + wl];

    int c0 = 0;
    for (int it = 0; it < (NN / CH) / 2; ++it, c0 += 2 * CH) {
        // prefetch chunk B (rows c0+CH .. c0+2CH-1) — always in-bounds
        #pragma unroll
        for (int t = 0; t < CH; ++t) bufB[t] = srow[(size_t)(c0 + CH + t) * WPB + wl];
        // process chunk A — scalar bit test (uniform) + vector AND only when kept
        #pragma unroll
        for (int t = 0; t < CH; ++t) {
            int i = c0 + t;
            unsigned long long kw = readlane_u64(keep, i >> 6);
            if ((kw >> (i & 63)) & 1ull) keep &= ~bufA[t];
        }
        // prefetch next chunk A (rows c0+2CH .. c0+3CH-1); last pair loads the
        // final chunk here (c0=1950 -> rows 1975..1999), consumed below as B?
        // no — consumed next iteration... for the LAST iteration this would be
        // out of bounds, so guard with the loop structure instead:
        if (it + 1 < (NN / CH) / 2) {
            #pragma unroll
            for (int t = 0; t < CH; ++t) bufA[t] = srow[(size_t)(c0 + 2 * CH + t) * WPB + wl];
        }
        // process chunk B
        #pragma unroll
        for (int t = 0; t < CH; ++t) {
            int i = c0 + CH + t;
            unsigned long long kw = readlane_u64(keep, i >> 6);
            if ((kw >> (i & 63)) & 1ull) keep &= ~bufB[t];
        }
    }

    // ---- emit first 100 kept in order ----
    int cnt = __popcll(keep);
    int base = 0, total = 0;
    for (int w2 = 0; w2 < 32; ++w2) {
        int c2 = __shfl(cnt, w2);
        if (w2 < wl) base += c2;
        total += c2;
    }

    if (lane < 32) {
        unsigned long long kk = keep;
        int r = base;
        while (kk) {
            int k = __builtin_ctzll(kk);
            kk &= kk - 1;
            if (r < MAXI) {
                int j = wl * 64 + k;
                float4 bx = ((const float4*)sboxes)[b * NN + j];
                float* o = out + ((size_t)b * MAXI + r) * 6;
                o[0] = bx.x; o[1] = bx.y; o[2] = bx.z; o[3] = bx.w;
                o[4] = (float)scls[b * NN + j];
                o[5] = sscore[b * NN + j];
            }
            ++r;
        }
    }
    for (int r = total + lane; r < MAXI; r += 64) {
        float* o = out + ((size_t)b * MAXI + r) * 6;
        #pragma unroll
        for (int q = 0; q < 6; ++q) o[q] = 0.f;
    }
}

extern "C" void kernel_launch(void* const* d_in, const int* in_sizes, int n_in,
                              void* d_out, int out_size, void* d_ws, size_t ws_size,
                              hipStream_t stream) {
    const float* rois   = (const float*)d_in[0];
    const float* probs  = (const float*)d_in[1];
    const float* deltas = (const float*)d_in[2];
    float* out = (float*)d_out;

    char* ws = (char*)d_ws;
    float* boxes  = (float*)(ws + 0);
    float* key    = (float*)(ws + 256000);
    int*   cls    = (int*)  (ws + 320000);
    float* sboxes = (float*)(ws + 384000);
    float* sscore = (float*)(ws + 640000);
    int*   scls   = (int*)  (ws + 704000);
    unsigned long long* vbits = (unsigned long long*)(ws + 768000);
    unsigned long long* sup   = (unsigned long long*)(ws + 770048);

    {
        int threads = BB * NN;
        int blocks = (threads + 255) / 256;
        k1_refine<<<blocks, 256, 0, stream>>>(rois, probs, deltas, boxes, key, cls, vbits);
    }
    {
        int threads = BB * NN;
        int blocks = (threads + 255) / 256;
        k2_rank<<<blocks, 256, 0, stream>>>(boxes, key, cls, sboxes, sscore, scls, vbits);
    }
    {
        int threads = BB * NN * WPB;
        int blocks = (threads + 255) / 256;
        k3_sup<<<blocks, 256, 0, stream>>>(sboxes, scls, sup);
    }
    {
        k4_scan<<<BB, 64, 0, stream>>>(sup, vbits, sboxes, sscore, scls, out);
    }
}